// Round 13
// baseline (692.039 us; speedup 1.0000x reference)
//
#include <hip/hip_runtime.h>
#include <hip/hip_bf16.h>
#include <math.h>

#define N_NODES 16384
#define T_TRI   65536
#define H_DIM   128
#define G_POOL  512
#define NITER   4
#define NLAY    4
#define RMAX    (T_TRI + 512)
#define MT32    (RMAX / 32)       // 2064 single-wave tiles of 32 rows

#define INV_STD 0.9999950000374996f

typedef __attribute__((ext_vector_type(8))) short bhalf8;
typedef __attribute__((ext_vector_type(4))) float f32x4;

__device__ __forceinline__ unsigned short f2b(float f) {
    unsigned int u = __float_as_uint(f);
    unsigned int r = (u + 0x7fffu + ((u >> 16) & 1u)) >> 16;
    return (unsigned short)r;
}
__device__ __forceinline__ float b2f(unsigned short b) {
    return __uint_as_float(((unsigned int)b) << 16);
}

// ---------------- group classification ----------------

__device__ __forceinline__ int group_of(int eij, int ejk, int nei) {
    return ((eij < nei) ? 0 : 2) + ((ejk < nei) ? 0 : 1);
}

__global__ void histboth_k(const int* __restrict__ edxjk, const int* __restrict__ edxij,
                           const int* __restrict__ neip, const int* __restrict__ eidx,
                           int* __restrict__ ints, int* __restrict__ cnt) {
    __shared__ int lc[4];
    if (threadIdx.x < 4) lc[threadIdx.x] = 0;
    __syncthreads();
    int t = blockIdx.x * 256 + threadIdx.x;
    int nei = *neip;
    int g = group_of(edxij[t], edxjk[t], nei);
    atomicAdd(&lc[g], 1);
    atomicAdd(&cnt[eidx[t]], 1);
    __syncthreads();
    if (threadIdx.x < 4) atomicAdd(&ints[threadIdx.x], lc[threadIdx.x]);
}

__global__ void scanoff_k(int* __restrict__ ints, int* __restrict__ cnt,
                          int* __restrict__ row_start) {
    __shared__ int part[256];
    int tid = threadIdx.x;
    if (tid == 0) {
        int a = 0;
        ints[8] = 0;
        for (int g = 0; g < 4; ++g) {
            a = (a + ints[g] + 127) & ~127;
            ints[9 + g] = a;
        }
    }
    int base = tid * 64;
    int s = 0;
    for (int q = 0; q < 64; ++q) s += cnt[base + q];
    part[tid] = s;
    __syncthreads();
    if (tid == 0) {
        int run = 0;
        for (int q = 0; q < 256; ++q) { int v = part[q]; part[q] = run; run += v; }
        row_start[N_NODES] = run;
    }
    __syncthreads();
    int p = part[tid];
    for (int q = 0; q < 64; ++q) {
        int c = cnt[base + q];
        row_start[base + q] = p;
        cnt[base + q] = p;
        p += c;
    }
}

__global__ void scatboth_k(const int* __restrict__ edxjk, const int* __restrict__ edxij,
                           const int* __restrict__ neip, const int* __restrict__ eidx,
                           int* __restrict__ ints, int* __restrict__ rowmap,
                           int* __restrict__ cursor, int* __restrict__ row_ids) {
    int t = blockIdx.x * 256 + threadIdx.x;
    int nei = *neip;
    int g = group_of(edxij[t], edxjk[t], nei);
    int lane = threadIdx.x & 63;
    unsigned long long msame = 0;
    #pragma unroll
    for (int q = 0; q < 4; ++q) {
        unsigned long long mq = __ballot(g == q);
        if (g == q) msame = mq;
    }
    int leader = __ffsll((long long)msame) - 1;
    int rank = __popcll(msame & ((1ull << lane) - 1ull));
    int base = 0;
    if (lane == leader) base = atomicAdd(&ints[4 + g], __popcll(msame));
    base = __shfl(base, leader);
    int pos = ints[8 + g] + base + rank;
    rowmap[pos] = t;
    int slot = atomicAdd(&cursor[eidx[t]], 1);
    row_ids[slot] = pos;
}

// ---------------- weight prep: LDS tile transpose, fp32 -> bf16 [n][k] ----------------

__global__ void t0_k(const float* __restrict__ W0, unsigned short* __restrict__ WT0) {
    __shared__ float t[32][33];
    int b = blockIdx.x;                 // 16 * 16 * 4 = 1024 tiles
    int ig = b >> 6;
    int kt = (b >> 2) & 15;
    int nt = b & 3;
    int tx = threadIdx.x & 31, ty = threadIdx.x >> 5;
    const float* src = W0 + ((size_t)ig * 512 + kt * 32) * 128 + nt * 32;
    #pragma unroll
    for (int q = 0; q < 4; ++q) { int r = q * 8 + ty; t[r][tx] = src[(size_t)r * 128 + tx]; }
    __syncthreads();
    unsigned short* dst = WT0 + ((size_t)ig * 128 + nt * 32) * 512 + kt * 32;
    #pragma unroll
    for (int q = 0; q < 4; ++q) { int r = q * 8 + ty; dst[(size_t)r * 512 + tx] = f2b(t[tx][r]); }
}

__global__ void th_k(const float* __restrict__ Wh, unsigned short* __restrict__ WTh) {
    __shared__ float t[32][33];
    int b = blockIdx.x;                 // 64 * 4 * 4 = 1024 tiles
    int ilg = b >> 4;
    int kt = (b >> 2) & 3;
    int nt = b & 3;
    int tx = threadIdx.x & 31, ty = threadIdx.x >> 5;
    const float* src = Wh + ((size_t)ilg * 128 + kt * 32) * 128 + nt * 32;
    #pragma unroll
    for (int q = 0; q < 4; ++q) { int r = q * 8 + ty; t[r][tx] = src[(size_t)r * 128 + tx]; }
    __syncthreads();
    unsigned short* dst = WTh + ((size_t)ilg * 128 + nt * 32) * 128 + kt * 32;
    #pragma unroll
    for (int q = 0; q < 4; ++q) { int r = q * 8 + ty; dst[(size_t)r * 128 + tx] = f2b(t[tx][r]); }
}

// ---------------- geo encoding (vectorized) ----------------

__global__ void geo_k(const float* __restrict__ pos, const int* __restrict__ eidx,
                      const float* __restrict__ Wg, const float* __restrict__ bg,
                      const float* __restrict__ gamg, const float* __restrict__ betg,
                      unsigned short* __restrict__ geob) {
    int t = blockIdx.x * 16 + (threadIdx.x >> 4);
    int h0 = (threadIdx.x & 15) * 8;
    int ni = eidx[t], nj = eidx[T_TRI + t], nk = eidx[2 * T_TRI + t];
    float ix = pos[2 * ni], iy = pos[2 * ni + 1];
    float jx = pos[2 * nj], jy = pos[2 * nj + 1];
    float kx = pos[2 * nk], ky = pos[2 * nk + 1];
    float v1x = jx - ix, v1y = jy - iy;
    float v2x = kx - jx, v2y = ky - jy;
    float dij = sqrtf(v1x * v1x + v1y * v1y);
    float djk = sqrtf(v2x * v2x + v2y * v2y);
    float cr = v1x * v2y - v1y * v2x;
    float dt = v1x * v2x + v1y * v2y;
    float th = atan2f(fabsf(cr), dt);
    unsigned int ov[4];
    #pragma unroll
    for (int q = 0; q < 4; ++q) {
        unsigned int lo = 0, hi = 0;
        #pragma unroll
        for (int e = 0; e < 2; ++e) {
            int h = h0 + q * 2 + e;
            float v = dij * Wg[h] + djk * Wg[128 + h] + th * Wg[256 + h] + bg[h];
            v = v * (gamg[h] * INV_STD) + betg[h];
            v = fmaxf(v, 0.0f);
            if (e == 0) lo = f2b(v); else hi = f2b(v);
        }
        ov[q] = lo | (hi << 16);
    }
    int4 o = { (int)ov[0], (int)ov[1], (int)ov[2], (int)ov[3] };
    *reinterpret_cast<int4*>(&geob[(size_t)t * 128 + h0]) = o;
}

// ---------------- barrier-free per-wave chain: 32 rows/wave, A direct-gather ----------------
// Single-wave block. Lane l owns A-rows {l&15, 16+(l&15)}; k-slice (l>>4)*8.
// GEMM0: A-fragments loaded straight from global (depth-4 rotating prefetch).
// Hidden layers: h in wave-private LDS (no __syncthreads anywhere), B from L2.

template<int SKIPNF>
__global__ __launch_bounds__(64) void chain_k(
    const unsigned short* __restrict__ nfb, const unsigned short* __restrict__ geob,
    const int* __restrict__ eidx, const int* __restrict__ rowmap,
    const int* __restrict__ aoff, const unsigned short* __restrict__ WT0,
    const float* __restrict__ b0, const float* __restrict__ g0, const float* __restrict__ be0,
    const unsigned short* __restrict__ WTh,
    const float* __restrict__ bhp, const float* __restrict__ ghp, const float* __restrict__ behp,
    const float* __restrict__ att, unsigned short* __restrict__ hfinal,
    int it) {
    __shared__ unsigned short shw[32 * 128];   // 8 KB wave-private h tile (swizzled)

    const int r0 = blockIdx.x * 32;
    int g = 0;
    if (r0 >= aoff[1]) g = 1;
    if (r0 >= aoff[2]) g = 2;
    if (r0 >= aoff[3]) g = 3;
    const int lane = threadIdx.x & 63;
    const int lr = lane & 15, lq = lane >> 4;

    // per-lane A rows: m=0 -> r0+lr, m=1 -> r0+16+lr
    int ttm[2];
    const unsigned short* pi[2];
    const unsigned short* pj[2];
    const unsigned short* pk[2];
    const unsigned short* pg[2];
    #pragma unroll
    for (int m = 0; m < 2; ++m) {
        int tt = rowmap[r0 + 16 * m + lr];
        ttm[m] = tt;
        int ts = tt < 0 ? 0 : tt;
        pg[m] = geob + (size_t)ts * 128;
        if (!SKIPNF) {
            pi[m] = nfb + (size_t)eidx[ts] * 128;
            pj[m] = nfb + (size_t)eidx[T_TRI + ts] * 128;
            pk[m] = nfb + (size_t)eidx[2 * T_TRI + ts] * 128;
        } else {
            pi[m] = pj[m] = pk[m] = pg[m];
        }
    }

    f32x4 acc[2][8];
    const f32x4 zero4 = {0.f, 0.f, 0.f, 0.f};
    #pragma unroll
    for (int m = 0; m < 2; ++m)
        #pragma unroll
        for (int n = 0; n < 8; ++n) acc[m][n] = zero4;

    // ---- GEMM0: 16 MFMA-k-steps of 32; A per-lane direct, depth-4 prefetch ----
    const unsigned short* Wt = WT0 + (size_t)(it * 4 + g) * 128 * 512;
    constexpr int KS0 = SKIPNF ? 12 : 0;

    auto loadA = [&](int ks, int m) -> int4 {
        const int region = ks >> 2;                    // constant after unroll
        const int off = (ks & 3) * 32 + lq * 8;
        const unsigned short* src =
            region == 0 ? pi[m] : region == 1 ? pj[m] : region == 2 ? pk[m] : pg[m];
        int4 v = {0, 0, 0, 0};
        if (ttm[m] >= 0) v = *reinterpret_cast<const int4*>(src + off);
        return v;
    };

    int4 pf[2][4];
    #pragma unroll
    for (int s = 0; s < 4; ++s) {
        pf[0][s] = loadA(KS0 + s, 0);
        pf[1][s] = loadA(KS0 + s, 1);
    }
    #pragma unroll
    for (int ks = KS0; ks < 16; ++ks) {
        const int slot = (ks - KS0) & 3;
        bhalf8 a0 = *reinterpret_cast<bhalf8*>(&pf[0][slot]);
        bhalf8 a1 = *reinterpret_cast<bhalf8*>(&pf[1][slot]);
        if (ks + 4 < 16) {
            pf[0][slot] = loadA(ks + 4, 0);
            pf[1][slot] = loadA(ks + 4, 1);
        }
        #pragma unroll
        for (int n = 0; n < 8; ++n) {
            bhalf8 bf = *reinterpret_cast<const bhalf8*>(
                Wt + (size_t)(16 * n + lr) * 512 + ks * 32 + lq * 8);
            acc[0][n] = __builtin_amdgcn_mfma_f32_16x16x32_bf16(a0, bf, acc[0][n], 0, 0, 0);
            acc[1][n] = __builtin_amdgcn_mfma_f32_16x16x32_bf16(a1, bf, acc[1][n], 0, 0, 0);
        }
    }

    // h0 = relu(bn(acc)) -> shw  (wave-private; no barrier needed)
    {
        const float* bb = b0 + (it * 4 + g) * 128;
        const float* gg = g0 + (it * 4 + g) * 128;
        const float* be = be0 + (it * 4 + g) * 128;
        #pragma unroll
        for (int n = 0; n < 8; ++n) {
            int col = 16 * n + lr;
            float sc = gg[col] * INV_STD;
            float bbc = bb[col], bec = be[col];
            int gc = col >> 3, cl = col & 7;
            #pragma unroll
            for (int m = 0; m < 2; ++m)
                #pragma unroll
                for (int r = 0; r < 4; ++r) {
                    int row = 16 * m + 4 * lq + r;
                    float v = fmaxf((acc[m][n][r] + bbc) * sc + bec, 0.0f);
                    shw[row * 128 + ((gc ^ (row & 7)) << 3) + cl] = f2b(v);
                }
        }
    }

    // ---- hidden layers: A from shw (same-wave RAW, lgkmcnt only), B from L2 ----
    for (int l = 0; l < NLAY; ++l) {
        const unsigned short* Wl = WTh + (size_t)((it * NLAY + l) * 4 + g) * 128 * 128;
        f32x4 hacc[2][8];
        #pragma unroll
        for (int m = 0; m < 2; ++m)
            #pragma unroll
            for (int n = 0; n < 8; ++n) hacc[m][n] = zero4;
        #pragma unroll
        for (int kk = 0; kk < 4; ++kk) {
            bhalf8 af[2];
            #pragma unroll
            for (int m = 0; m < 2; ++m) {
                int row = 16 * m + lr;
                int gc = (4 * kk + lq) ^ (row & 7);
                af[m] = *reinterpret_cast<const bhalf8*>(&shw[row * 128 + (gc << 3)]);
            }
            #pragma unroll
            for (int n = 0; n < 8; ++n) {
                bhalf8 bf = *reinterpret_cast<const bhalf8*>(
                    Wl + (size_t)(16 * n + lr) * 128 + kk * 32 + lq * 8);
                hacc[0][n] = __builtin_amdgcn_mfma_f32_16x16x32_bf16(af[0], bf, hacc[0][n], 0, 0, 0);
                hacc[1][n] = __builtin_amdgcn_mfma_f32_16x16x32_bf16(af[1], bf, hacc[1][n], 0, 0, 0);
            }
        }
        const int ilg = (it * NLAY + l) * 4 + g;
        const float* bb = bhp + (size_t)ilg * 128;
        const float* gg = ghp + (size_t)ilg * 128;
        const float* be = behp + (size_t)ilg * 128;
        float attg = (l == NLAY - 1) ? att[g] : 1.0f;
        #pragma unroll
        for (int n = 0; n < 8; ++n) {
            int col = 16 * n + lr;
            float sc = gg[col] * INV_STD;
            float bbc = bb[col], bec = be[col];
            int gc = col >> 3, cl = col & 7;
            #pragma unroll
            for (int m = 0; m < 2; ++m)
                #pragma unroll
                for (int r = 0; r < 4; ++r) {
                    int row = 16 * m + 4 * lq + r;
                    float v = fmaxf((hacc[m][n][r] + bbc) * sc + bec, 0.0f) * attg;
                    shw[row * 128 + ((gc ^ (row & 7)) << 3) + cl] = f2b(v);
                }
        }
    }

    // ---- copy out: coalesced int4 stores (8 per lane) ----
    #pragma unroll
    for (int p = 0; p < 8; ++p) {
        int idx = p * 64 + lane;          // 512 granule-slots: 32 rows x 16 granules
        int row = idx >> 4, gd = idx & 15;
        int4 v = *reinterpret_cast<const int4*>(&shw[row * 128 + ((gd ^ (row & 7)) << 3)]);
        *reinterpret_cast<int4*>(&hfinal[(size_t)(r0 + row) * 128 + gd * 8]) = v;
    }
}

// ---------------- per-node CSR reduce: nf = segment_sum; fused cvt + pool ----------------

__global__ void reduce_k(const unsigned short* __restrict__ hfinal,
                         const int* __restrict__ row_start, const int* __restrict__ row_ids,
                         const int* __restrict__ ntf, unsigned short* __restrict__ nfb,
                         float* __restrict__ emb, int itoff) {
    int n = blockIdx.x * 2 + (threadIdx.x >> 7);
    int c = threadIdx.x & 127;
    int s = row_start[n], e = row_start[n + 1];
    float acc = 0.0f;
    for (int r = s; r < e; ++r) {
        int rid = row_ids[r];
        acc += b2f(hfinal[(size_t)rid * 128 + c]);
    }
    nfb[(size_t)n * 128 + c] = f2b(acc);
    atomicAdd(&emb[(size_t)ntf[n] * 512 + itoff + c], acc);
}

__global__ void clamp_k(const float* __restrict__ emb, float* __restrict__ out) {
    int i = blockIdx.x * 256 + threadIdx.x;
    out[i] = fminf(emb[i], 1.0e6f);
}

// ---------------- launch ----------------

extern "C" void kernel_launch(void* const* d_in, const int* in_sizes, int n_in,
                              void* d_out, int out_size, void* d_ws, size_t ws_size,
                              hipStream_t stream) {
    (void)in_sizes; (void)n_in; (void)out_size; (void)ws_size;
    const float* pos   = (const float*)d_in[0];
    const int*   eidx  = (const int*)d_in[1];
    const int*   edxjk = (const int*)d_in[2];
    const int*   edxij = (const int*)d_in[3];
    const int*   neip  = (const int*)d_in[4];
    const int*   ntf   = (const int*)d_in[5];
    const float* Wg    = (const float*)d_in[6];
    const float* bg    = (const float*)d_in[7];
    const float* gamg  = (const float*)d_in[8];
    const float* betg  = (const float*)d_in[9];
    const float* W0    = (const float*)d_in[10];
    const float* b0    = (const float*)d_in[11];
    const float* g0    = (const float*)d_in[12];
    const float* be0   = (const float*)d_in[13];
    const float* Wh    = (const float*)d_in[14];
    const float* bhp   = (const float*)d_in[15];
    const float* ghp   = (const float*)d_in[16];
    const float* behp  = (const float*)d_in[17];
    const float* att   = (const float*)d_in[18];

    char* w = (char*)d_ws;
    size_t off = 0;
    auto alloc = [&](size_t b) -> char* {
        char* p = w + off;
        off += (b + 255) & ~(size_t)255;
        return p;
    };
    int* ints            = (int*)alloc(256);
    int* rowmap          = (int*)alloc((size_t)RMAX * 4);
    int* cnt             = (int*)alloc((size_t)N_NODES * 4);
    int* row_start       = (int*)alloc((size_t)(N_NODES + 1) * 4);
    int* row_ids         = (int*)alloc((size_t)T_TRI * 4);
    unsigned short* WT0  = (unsigned short*)alloc((size_t)16 * 128 * 512 * 2);
    unsigned short* WTh  = (unsigned short*)alloc((size_t)64 * 128 * 128 * 2);
    unsigned short* geob = (unsigned short*)alloc((size_t)T_TRI * 128 * 2);
    unsigned short* nfb  = (unsigned short*)alloc((size_t)N_NODES * 128 * 2);
    unsigned short* hfin = (unsigned short*)alloc((size_t)RMAX * 128 * 2);
    float* emb           = (float*)alloc((size_t)G_POOL * 512 * 4);

    hipMemsetAsync(ints, 0, 256, stream);
    hipMemsetAsync(rowmap, 0xFF, (size_t)RMAX * 4, stream);
    hipMemsetAsync(cnt, 0, (size_t)N_NODES * 4, stream);
    hipMemsetAsync(emb, 0, (size_t)G_POOL * 512 * 4, stream);

    histboth_k<<<256, 256, 0, stream>>>(edxjk, edxij, neip, eidx, ints, cnt);
    scanoff_k<<<1, 256, 0, stream>>>(ints, cnt, row_start);
    scatboth_k<<<256, 256, 0, stream>>>(edxjk, edxij, neip, eidx, ints, rowmap, cnt, row_ids);
    t0_k<<<1024, 256, 0, stream>>>(W0, WT0);
    th_k<<<1024, 256, 0, stream>>>(Wh, WTh);
    geo_k<<<T_TRI / 16, 256, 0, stream>>>(pos, eidx, Wg, bg, gamg, betg, geob);

    for (int it = 0; it < NITER; ++it) {
        if (it == 0)
            chain_k<1><<<MT32, 64, 0, stream>>>(nfb, geob, eidx, rowmap, ints + 8, WT0, b0, g0, be0,
                                                WTh, bhp, ghp, behp, att, hfin, it);
        else
            chain_k<0><<<MT32, 64, 0, stream>>>(nfb, geob, eidx, rowmap, ints + 8, WT0, b0, g0, be0,
                                                WTh, bhp, ghp, behp, att, hfin, it);
        reduce_k<<<N_NODES / 2, 256, 0, stream>>>(hfin, row_start, row_ids, ntf, nfb, emb, it * 128);
    }

    clamp_k<<<1024, 256, 0, stream>>>(emb, (float*)d_out);
}

// Round 14
// 468.589 us; speedup vs baseline: 1.4769x; 1.4769x over previous
//
#include <hip/hip_runtime.h>
#include <hip/hip_bf16.h>
#include <math.h>

#define N_NODES 16384
#define T_TRI   65536
#define H_DIM   128
#define G_POOL  512
#define NITER   4
#define NLAY    4
#define RMAX    (T_TRI + 512)
#define MT64    (RMAX / 64)       // 1032 tiles of 64 rows

#define INV_STD 0.9999950000374996f

typedef __attribute__((ext_vector_type(8))) short bhalf8;
typedef __attribute__((ext_vector_type(4))) float f32x4;
typedef __attribute__((address_space(3))) void lds_t;
typedef __attribute__((address_space(1))) const void gmem_t;

__device__ __forceinline__ unsigned short f2b(float f) {
    unsigned int u = __float_as_uint(f);
    unsigned int r = (u + 0x7fffu + ((u >> 16) & 1u)) >> 16;
    return (unsigned short)r;
}
__device__ __forceinline__ float b2f(unsigned short b) {
    return __uint_as_float(((unsigned int)b) << 16);
}

// ---------------- group classification ----------------

__device__ __forceinline__ int group_of(int eij, int ejk, int nei) {
    return ((eij < nei) ? 0 : 2) + ((ejk < nei) ? 0 : 1);
}

__global__ void histboth_k(const int* __restrict__ edxjk, const int* __restrict__ edxij,
                           const int* __restrict__ neip, const int* __restrict__ eidx,
                           int* __restrict__ ints, int* __restrict__ cnt) {
    __shared__ int lc[4];
    if (threadIdx.x < 4) lc[threadIdx.x] = 0;
    __syncthreads();
    int t = blockIdx.x * 256 + threadIdx.x;
    int nei = *neip;
    int g = group_of(edxij[t], edxjk[t], nei);
    atomicAdd(&lc[g], 1);
    atomicAdd(&cnt[eidx[t]], 1);
    __syncthreads();
    if (threadIdx.x < 4) atomicAdd(&ints[threadIdx.x], lc[threadIdx.x]);
}

__global__ void scanoff_k(int* __restrict__ ints, int* __restrict__ cnt,
                          int* __restrict__ row_start) {
    __shared__ int part[256];
    int tid = threadIdx.x;
    if (tid == 0) {
        int a = 0;
        ints[8] = 0;
        for (int g = 0; g < 4; ++g) {
            a = (a + ints[g] + 127) & ~127;
            ints[9 + g] = a;
        }
    }
    int base = tid * 64;
    int s = 0;
    for (int q = 0; q < 64; ++q) s += cnt[base + q];
    part[tid] = s;
    __syncthreads();
    if (tid == 0) {
        int run = 0;
        for (int q = 0; q < 256; ++q) { int v = part[q]; part[q] = run; run += v; }
        row_start[N_NODES] = run;
    }
    __syncthreads();
    int p = part[tid];
    for (int q = 0; q < 64; ++q) {
        int c = cnt[base + q];
        row_start[base + q] = p;
        cnt[base + q] = p;
        p += c;
    }
}

__global__ void scatboth_k(const int* __restrict__ edxjk, const int* __restrict__ edxij,
                           const int* __restrict__ neip, const int* __restrict__ eidx,
                           int* __restrict__ ints, int* __restrict__ rowmap,
                           int* __restrict__ cursor, int* __restrict__ row_ids) {
    int t = blockIdx.x * 256 + threadIdx.x;
    int nei = *neip;
    int g = group_of(edxij[t], edxjk[t], nei);
    int lane = threadIdx.x & 63;
    unsigned long long msame = 0;
    #pragma unroll
    for (int q = 0; q < 4; ++q) {
        unsigned long long mq = __ballot(g == q);
        if (g == q) msame = mq;
    }
    int leader = __ffsll((long long)msame) - 1;
    int rank = __popcll(msame & ((1ull << lane) - 1ull));
    int base = 0;
    if (lane == leader) base = atomicAdd(&ints[4 + g], __popcll(msame));
    base = __shfl(base, leader);
    int pos = ints[8 + g] + base + rank;
    rowmap[pos] = t;
    int slot = atomicAdd(&cursor[eidx[t]], 1);
    row_ids[slot] = pos;
}

// ---------------- weight prep: LDS tile transpose, fp32 -> bf16 [n][k] ----------------

__global__ void t0_k(const float* __restrict__ W0, unsigned short* __restrict__ WT0) {
    __shared__ float t[32][33];
    int b = blockIdx.x;                 // 16 * 16 * 4 = 1024 tiles
    int ig = b >> 6;
    int kt = (b >> 2) & 15;
    int nt = b & 3;
    int tx = threadIdx.x & 31, ty = threadIdx.x >> 5;
    const float* src = W0 + ((size_t)ig * 512 + kt * 32) * 128 + nt * 32;
    #pragma unroll
    for (int q = 0; q < 4; ++q) { int r = q * 8 + ty; t[r][tx] = src[(size_t)r * 128 + tx]; }
    __syncthreads();
    unsigned short* dst = WT0 + ((size_t)ig * 128 + nt * 32) * 512 + kt * 32;
    #pragma unroll
    for (int q = 0; q < 4; ++q) { int r = q * 8 + ty; dst[(size_t)r * 512 + tx] = f2b(t[tx][r]); }
}

__global__ void th_k(const float* __restrict__ Wh, unsigned short* __restrict__ WTh) {
    __shared__ float t[32][33];
    int b = blockIdx.x;                 // 64 * 4 * 4 = 1024 tiles
    int ilg = b >> 4;
    int kt = (b >> 2) & 3;
    int nt = b & 3;
    int tx = threadIdx.x & 31, ty = threadIdx.x >> 5;
    const float* src = Wh + ((size_t)ilg * 128 + kt * 32) * 128 + nt * 32;
    #pragma unroll
    for (int q = 0; q < 4; ++q) { int r = q * 8 + ty; t[r][tx] = src[(size_t)r * 128 + tx]; }
    __syncthreads();
    unsigned short* dst = WTh + ((size_t)ilg * 128 + nt * 32) * 128 + kt * 32;
    #pragma unroll
    for (int q = 0; q < 4; ++q) { int r = q * 8 + ty; dst[(size_t)r * 128 + tx] = f2b(t[tx][r]); }
}

// ---------------- geo encoding (vectorized) ----------------

__global__ void geo_k(const float* __restrict__ pos, const int* __restrict__ eidx,
                      const float* __restrict__ Wg, const float* __restrict__ bg,
                      const float* __restrict__ gamg, const float* __restrict__ betg,
                      unsigned short* __restrict__ geob) {
    int t = blockIdx.x * 16 + (threadIdx.x >> 4);
    int h0 = (threadIdx.x & 15) * 8;
    int ni = eidx[t], nj = eidx[T_TRI + t], nk = eidx[2 * T_TRI + t];
    float ix = pos[2 * ni], iy = pos[2 * ni + 1];
    float jx = pos[2 * nj], jy = pos[2 * nj + 1];
    float kx = pos[2 * nk], ky = pos[2 * nk + 1];
    float v1x = jx - ix, v1y = jy - iy;
    float v2x = kx - jx, v2y = ky - jy;
    float dij = sqrtf(v1x * v1x + v1y * v1y);
    float djk = sqrtf(v2x * v2x + v2y * v2y);
    float cr = v1x * v2y - v1y * v2x;
    float dt = v1x * v2x + v1y * v2y;
    float th = atan2f(fabsf(cr), dt);
    unsigned int ov[4];
    #pragma unroll
    for (int q = 0; q < 4; ++q) {
        unsigned int lo = 0, hi = 0;
        #pragma unroll
        for (int e = 0; e < 2; ++e) {
            int h = h0 + q * 2 + e;
            float v = dij * Wg[h] + djk * Wg[128 + h] + th * Wg[256 + h] + bg[h];
            v = v * (gamg[h] * INV_STD) + betg[h];
            v = fmaxf(v, 0.0f);
            if (e == 0) lo = f2b(v); else hi = f2b(v);
        }
        ov[q] = lo | (hi << 16);
    }
    int4 o = { (int)ov[0], (int)ov[1], (int)ov[2], (int)ov[3] };
    *reinterpret_cast<int4*>(&geob[(size_t)t * 128 + h0]) = o;
}

// ---------------- fused chain, 64-row tiles: A staged upfront via global_load_lds ----
// GEMM0: ALL A-tiles async-staged to LDS at kernel start (one vmcnt drain),
// then barrier-free MFMA k-loop; B reg-fragments from L2. Hidden layers as before.

template<int SKIPNF>
__global__ __launch_bounds__(256, 2) void chain_k(
    const unsigned short* __restrict__ nfb, const unsigned short* __restrict__ geob,
    const int* __restrict__ eidx, const int* __restrict__ rowmap,
    const int* __restrict__ aoff, const unsigned short* __restrict__ WT0,
    const float* __restrict__ b0, const float* __restrict__ g0, const float* __restrict__ be0,
    const unsigned short* __restrict__ WTh,
    const float* __restrict__ bhp, const float* __restrict__ ghp, const float* __restrict__ behp,
    const float* __restrict__ att, unsigned short* __restrict__ hfinal,
    int it) {
    constexpr int KSTEPS = SKIPNF ? 2 : 8;     // 64-col k-steps
    constexpr int KS0    = SKIPNF ? 6 : 0;     // first absolute step (geo-only at it=0)
    __shared__ unsigned short sa[KSTEPS * 64 * 64];   // A stage (8KB/step); reused as h tile
    unsigned short* sh = sa;                          // 64 x 128 h tile (16KB) after GEMM0

    const int r0 = blockIdx.x * 64;
    int g = 0;
    if (r0 >= aoff[1]) g = 1;
    if (r0 >= aoff[2]) g = 2;
    if (r0 >= aoff[3]) g = 3;
    const int tid = threadIdx.x;
    const int lane = tid & 63;
    const int w = tid >> 6;              // wave id = n-strip
    const int lr = lane & 15, lq = lane >> 4;

    // staging: lane covers rows w*16 + q*8 + (lane>>3), q=0,1; granule slot lane&7.
    // swizzle X[row][gd] = data[gd ^ (row&7)]; row&7 == lane>>3 -> source granule:
    const int dcol = ((lane & 7) ^ (lane >> 3)) * 8;
    const unsigned short* psrc[2][4];   // [q][region]
    #pragma unroll
    for (int q = 0; q < 2; ++q) {
        int row = w * 16 + q * 8 + (lane >> 3);
        int tt = rowmap[r0 + row];
        int ts = tt < 0 ? 0 : tt;       // pad rows read row 0: finite garbage, never consumed
        psrc[q][3] = geob + (size_t)ts * 128;
        if (!SKIPNF) {
            psrc[q][0] = nfb + (size_t)eidx[ts] * 128;
            psrc[q][1] = nfb + (size_t)eidx[T_TRI + ts] * 128;
            psrc[q][2] = nfb + (size_t)eidx[2 * T_TRI + ts] * 128;
        }
    }

    // issue ALL A-staging loads async (no VGPR round-trip, linear LDS dest)
    #pragma unroll
    for (int s = 0; s < KSTEPS; ++s) {
        const int ks = KS0 + s;
        const int region = ks >> 1;          // 0:nf[i] 1:nf[j] 2:nf[k] 3:geo
        const int half = (ks & 1) * 64;
        #pragma unroll
        for (int q = 0; q < 2; ++q) {
            const unsigned short* gsrc = psrc[q][region] + half + dcol;
            unsigned short* ldst = &sa[(s * 64 + w * 16 + q * 8) * 64];
            __builtin_amdgcn_global_load_lds((gmem_t*)gsrc, (lds_t*)ldst, 16, 0, 0);
        }
    }

    f32x4 acc[4][2];
    const f32x4 zero4 = {0.f, 0.f, 0.f, 0.f};
    #pragma unroll
    for (int m = 0; m < 4; ++m)
        #pragma unroll
        for (int n = 0; n < 2; ++n) acc[m][n] = zero4;

    __syncthreads();   // single drain of all staging loads

    // ---- GEMM0: barrier-free k-loop; A from LDS, B reg-fragments from L2 ----
    const unsigned short* Wt = WT0 + (size_t)(it * 4 + g) * 128 * 512;
    #pragma unroll
    for (int s = 0; s < KSTEPS; ++s) {
        const int kabs = (KS0 + s) * 64;
        const unsigned short* As = &sa[s * 64 * 64];
        bhalf8 rbf[2][2];
        #pragma unroll
        for (int n = 0; n < 2; ++n) {
            int nn = 32 * w + 16 * n + lr;
            #pragma unroll
            for (int ks2 = 0; ks2 < 2; ++ks2)
                rbf[n][ks2] = *reinterpret_cast<const bhalf8*>(
                    Wt + (size_t)nn * 512 + kabs + ks2 * 32 + lq * 8);
        }
        #pragma unroll
        for (int ks2 = 0; ks2 < 2; ++ks2) {
            bhalf8 af[4];
            #pragma unroll
            for (int m = 0; m < 4; ++m) {
                int row = 16 * m + lr;
                int c8 = (4 * ks2 + lq) ^ (row & 7);
                af[m] = *reinterpret_cast<const bhalf8*>(&As[row * 64 + (c8 << 3)]);
            }
            #pragma unroll
            for (int m = 0; m < 4; ++m)
                #pragma unroll
                for (int n = 0; n < 2; ++n)
                    acc[m][n] = __builtin_amdgcn_mfma_f32_16x16x32_bf16(af[m], rbf[n][ks2], acc[m][n], 0, 0, 0);
        }
    }
    __syncthreads();   // all reads of sa done before h-tile overwrite

    // h0 = relu(bn(acc)) -> sh
    {
        const float* bb = b0 + (it * 4 + g) * 128;
        const float* gg = g0 + (it * 4 + g) * 128;
        const float* be = be0 + (it * 4 + g) * 128;
        #pragma unroll
        for (int n = 0; n < 2; ++n) {
            int col = 32 * w + 16 * n + lr;
            float sc = gg[col] * INV_STD;
            float bbc = bb[col], bec = be[col];
            int gc = col >> 3, cl = col & 7;
            #pragma unroll
            for (int m = 0; m < 4; ++m)
                #pragma unroll
                for (int r = 0; r < 4; ++r) {
                    int row = 16 * m + 4 * lq + r;
                    float v = fmaxf((acc[m][n][r] + bbc) * sc + bec, 0.0f);
                    sh[row * 128 + ((gc ^ (row & 7)) << 3) + cl] = f2b(v);
                }
        }
    }
    __syncthreads();

    // ---- hidden layers: A from sh, B reg-fragments from L2 ----
    for (int l = 0; l < NLAY; ++l) {
        const unsigned short* Wl = WTh + (size_t)((it * NLAY + l) * 4 + g) * 128 * 128;
        #pragma unroll
        for (int m = 0; m < 4; ++m)
            #pragma unroll
            for (int n = 0; n < 2; ++n) acc[m][n] = zero4;
        #pragma unroll
        for (int kk = 0; kk < 4; ++kk) {
            bhalf8 af[4], bf[2];
            #pragma unroll
            for (int n = 0; n < 2; ++n) {
                int nn = 32 * w + 16 * n + lr;
                bf[n] = *reinterpret_cast<const bhalf8*>(Wl + (size_t)nn * 128 + kk * 32 + lq * 8);
            }
            #pragma unroll
            for (int m = 0; m < 4; ++m) {
                int row = 16 * m + lr;
                int gc = (4 * kk + lq) ^ (row & 7);
                af[m] = *reinterpret_cast<const bhalf8*>(&sh[row * 128 + (gc << 3)]);
            }
            #pragma unroll
            for (int m = 0; m < 4; ++m)
                #pragma unroll
                for (int n = 0; n < 2; ++n)
                    acc[m][n] = __builtin_amdgcn_mfma_f32_16x16x32_bf16(af[m], bf[n], acc[m][n], 0, 0, 0);
        }
        __syncthreads();   // all reads of sh done before overwrite
        if (l + 1 < NLAY) {
            const int ilg = (it * NLAY + l) * 4 + g;
            const float* bb = bhp + (size_t)ilg * 128;
            const float* gg = ghp + (size_t)ilg * 128;
            const float* be = behp + (size_t)ilg * 128;
            #pragma unroll
            for (int n = 0; n < 2; ++n) {
                int col = 32 * w + 16 * n + lr;
                float sc = gg[col] * INV_STD;
                float bbc = bb[col], bec = be[col];
                int gc = col >> 3, cl = col & 7;
                #pragma unroll
                for (int m = 0; m < 4; ++m)
                    #pragma unroll
                    for (int r = 0; r < 4; ++r) {
                        int row = 16 * m + 4 * lq + r;
                        float v = fmaxf((acc[m][n][r] + bbc) * sc + bec, 0.0f);
                        sh[row * 128 + ((gc ^ (row & 7)) << 3) + cl] = f2b(v);
                    }
            }
            __syncthreads();
        }
    }

    // ---- epilogue: hfinal = att * relu(bn(acc)) via sh, coalesced int4 stores ----
    {
        const int ilg = (it * NLAY + (NLAY - 1)) * 4 + g;
        const float* bb = bhp + (size_t)ilg * 128;
        const float* gg = ghp + (size_t)ilg * 128;
        const float* be = behp + (size_t)ilg * 128;
        float attg = att[g];
        #pragma unroll
        for (int n = 0; n < 2; ++n) {
            int col = 32 * w + 16 * n + lr;
            float sc = gg[col] * INV_STD;
            float bbc = bb[col], bec = be[col];
            int gc = col >> 3, cl = col & 7;
            #pragma unroll
            for (int m = 0; m < 4; ++m)
                #pragma unroll
                for (int r = 0; r < 4; ++r) {
                    int row = 16 * m + 4 * lq + r;
                    float v = fmaxf((acc[m][n][r] + bbc) * sc + bec, 0.0f) * attg;
                    sh[row * 128 + ((gc ^ (row & 7)) << 3) + cl] = f2b(v);
                }
        }
    }
    __syncthreads();
    #pragma unroll
    for (int p = 0; p < 4; ++p) {
        int idx = p * 256 + tid;
        int row = idx >> 4, gd = idx & 15;
        int4 v = *reinterpret_cast<const int4*>(&sh[row * 128 + ((gd ^ (row & 7)) << 3)]);
        *reinterpret_cast<int4*>(&hfinal[(size_t)(r0 + row) * 128 + gd * 8]) = v;
    }
}

// ---------------- per-node CSR reduce: nf = segment_sum; fused cvt + pool ----------------

__global__ void reduce_k(const unsigned short* __restrict__ hfinal,
                         const int* __restrict__ row_start, const int* __restrict__ row_ids,
                         const int* __restrict__ ntf, unsigned short* __restrict__ nfb,
                         float* __restrict__ emb, int itoff) {
    int n = blockIdx.x * 2 + (threadIdx.x >> 7);
    int c = threadIdx.x & 127;
    int s = row_start[n], e = row_start[n + 1];
    float acc = 0.0f;
    for (int r = s; r < e; ++r) {
        int rid = row_ids[r];
        acc += b2f(hfinal[(size_t)rid * 128 + c]);
    }
    nfb[(size_t)n * 128 + c] = f2b(acc);
    atomicAdd(&emb[(size_t)ntf[n] * 512 + itoff + c], acc);
}

__global__ void clamp_k(const float* __restrict__ emb, float* __restrict__ out) {
    int i = blockIdx.x * 256 + threadIdx.x;
    out[i] = fminf(emb[i], 1.0e6f);
}

// ---------------- launch ----------------

extern "C" void kernel_launch(void* const* d_in, const int* in_sizes, int n_in,
                              void* d_out, int out_size, void* d_ws, size_t ws_size,
                              hipStream_t stream) {
    (void)in_sizes; (void)n_in; (void)out_size; (void)ws_size;
    const float* pos   = (const float*)d_in[0];
    const int*   eidx  = (const int*)d_in[1];
    const int*   edxjk = (const int*)d_in[2];
    const int*   edxij = (const int*)d_in[3];
    const int*   neip  = (const int*)d_in[4];
    const int*   ntf   = (const int*)d_in[5];
    const float* Wg    = (const float*)d_in[6];
    const float* bg    = (const float*)d_in[7];
    const float* gamg  = (const float*)d_in[8];
    const float* betg  = (const float*)d_in[9];
    const float* W0    = (const float*)d_in[10];
    const float* b0    = (const float*)d_in[11];
    const float* g0    = (const float*)d_in[12];
    const float* be0   = (const float*)d_in[13];
    const float* Wh    = (const float*)d_in[14];
    const float* bhp   = (const float*)d_in[15];
    const float* ghp   = (const float*)d_in[16];
    const float* behp  = (const float*)d_in[17];
    const float* att   = (const float*)d_in[18];

    char* w = (char*)d_ws;
    size_t off = 0;
    auto alloc = [&](size_t b) -> char* {
        char* p = w + off;
        off += (b + 255) & ~(size_t)255;
        return p;
    };
    int* ints            = (int*)alloc(256);
    int* rowmap          = (int*)alloc((size_t)RMAX * 4);
    int* cnt             = (int*)alloc((size_t)N_NODES * 4);
    int* row_start       = (int*)alloc((size_t)(N_NODES + 1) * 4);
    int* row_ids         = (int*)alloc((size_t)T_TRI * 4);
    unsigned short* WT0  = (unsigned short*)alloc((size_t)16 * 128 * 512 * 2);
    unsigned short* WTh  = (unsigned short*)alloc((size_t)64 * 128 * 128 * 2);
    unsigned short* geob = (unsigned short*)alloc((size_t)T_TRI * 128 * 2);
    unsigned short* nfb  = (unsigned short*)alloc((size_t)N_NODES * 128 * 2);
    unsigned short* hfin = (unsigned short*)alloc((size_t)RMAX * 128 * 2);
    float* emb           = (float*)alloc((size_t)G_POOL * 512 * 4);

    hipMemsetAsync(ints, 0, 256, stream);
    hipMemsetAsync(rowmap, 0xFF, (size_t)RMAX * 4, stream);
    hipMemsetAsync(cnt, 0, (size_t)N_NODES * 4, stream);
    hipMemsetAsync(emb, 0, (size_t)G_POOL * 512 * 4, stream);

    histboth_k<<<256, 256, 0, stream>>>(edxjk, edxij, neip, eidx, ints, cnt);
    scanoff_k<<<1, 256, 0, stream>>>(ints, cnt, row_start);
    scatboth_k<<<256, 256, 0, stream>>>(edxjk, edxij, neip, eidx, ints, rowmap, cnt, row_ids);
    t0_k<<<1024, 256, 0, stream>>>(W0, WT0);
    th_k<<<1024, 256, 0, stream>>>(Wh, WTh);
    geo_k<<<T_TRI / 16, 256, 0, stream>>>(pos, eidx, Wg, bg, gamg, betg, geob);

    for (int it = 0; it < NITER; ++it) {
        if (it == 0)
            chain_k<1><<<MT64, 256, 0, stream>>>(nfb, geob, eidx, rowmap, ints + 8, WT0, b0, g0, be0,
                                                 WTh, bhp, ghp, behp, att, hfin, it);
        else
            chain_k<0><<<MT64, 256, 0, stream>>>(nfb, geob, eidx, rowmap, ints + 8, WT0, b0, g0, be0,
                                                 WTh, bhp, ghp, behp, att, hfin, it);
        reduce_k<<<N_NODES / 2, 256, 0, stream>>>(hfin, row_start, row_ids, ntf, nfb, emb, it * 128);
    }

    clamp_k<<<1024, 256, 0, stream>>>(emb, (float*)d_out);
}